// Round 1
// baseline (77.519 us; speedup 1.0000x reference)
//
#include <hip/hip_runtime.h>
#include <math.h>

#define NFR 8
#define DD 2048
#define NS 25
#define NB 64
#define NPAIR (NS*NB)          // 1600
#define NITER 32
#define TGT_OFF (NPAIR*100)    // float offset of target-gram region in ws
// ws usage: 1600*100 + 64*36 = 162304 floats = 649 KB

__device__ __forceinline__ float bfly8(float x) {
    x += __shfl_xor(x, 1, 8);
    x += __shfl_xor(x, 2, 8);
    x += __shfl_xor(x, 4, 8);
    return x;
}

// One wave per (s,b) pair: 36 sup-sup dots (upper tri) + 64 sup-tgt cross dots.
// Waves 1600..1663: 36 tgt-tgt dots for b = wave-1600.
__global__ __launch_bounds__(256) void gram_kernel(const float* __restrict__ sup,
                                                   const float* __restrict__ tgt,
                                                   float* __restrict__ ws) {
    const int wave = blockIdx.x * 4 + (threadIdx.x >> 6);
    const int lane = threadIdx.x & 63;
    if (wave < NPAIR) {
        const float* __restrict__ sr = sup + (size_t)wave * (NFR*DD);
        const float* __restrict__ tr = tgt + (size_t)(wave & (NB-1)) * (NFR*DD);
        float ass[36], ax[64];
        #pragma unroll
        for (int i = 0; i < 36; ++i) ass[i] = 0.f;
        #pragma unroll
        for (int i = 0; i < 64; ++i) ax[i] = 0.f;
        for (int t = 0; t < 16; ++t) {
            const int d0 = t*128 + lane*2;
            float2 sv[8], tv[8];
            #pragma unroll
            for (int k = 0; k < 8; ++k) sv[k] = *(const float2*)(sr + k*DD + d0);
            #pragma unroll
            for (int k = 0; k < 8; ++k) tv[k] = *(const float2*)(tr + k*DD + d0);
            #pragma unroll
            for (int k = 0; k < 8; ++k) {
                #pragma unroll
                for (int l = k; l < 8; ++l) {
                    const int i = k*8 + l - k*(k+1)/2;
                    ass[i] = fmaf(sv[k].x, sv[l].x, ass[i]);
                    ass[i] = fmaf(sv[k].y, sv[l].y, ass[i]);
                }
            }
            #pragma unroll
            for (int k = 0; k < 8; ++k) {
                #pragma unroll
                for (int l = 0; l < 8; ++l) {
                    ax[k*8+l] = fmaf(sv[k].x, tv[l].x, ax[k*8+l]);
                    ax[k*8+l] = fmaf(sv[k].y, tv[l].y, ax[k*8+l]);
                }
            }
        }
        #pragma unroll
        for (int i = 0; i < 36; ++i) {
            #pragma unroll
            for (int m = 32; m >= 1; m >>= 1) ass[i] += __shfl_xor(ass[i], m, 64);
        }
        #pragma unroll
        for (int i = 0; i < 64; ++i) {
            #pragma unroll
            for (int m = 32; m >= 1; m >>= 1) ax[i] += __shfl_xor(ax[i], m, 64);
        }
        if (lane == 0) {
            float* o = ws + (size_t)wave * 100;
            #pragma unroll
            for (int i = 0; i < 36; ++i) o[i] = ass[i];
            #pragma unroll
            for (int i = 0; i < 64; ++i) o[36+i] = ax[i];
        }
    } else if (wave < NPAIR + NB) {
        const int b = wave - NPAIR;
        const float* __restrict__ tr = tgt + (size_t)b * (NFR*DD);
        float ass[36];
        #pragma unroll
        for (int i = 0; i < 36; ++i) ass[i] = 0.f;
        for (int t = 0; t < 16; ++t) {
            const int d0 = t*128 + lane*2;
            float2 tv[8];
            #pragma unroll
            for (int k = 0; k < 8; ++k) tv[k] = *(const float2*)(tr + k*DD + d0);
            #pragma unroll
            for (int k = 0; k < 8; ++k) {
                #pragma unroll
                for (int l = k; l < 8; ++l) {
                    const int i = k*8 + l - k*(k+1)/2;
                    ass[i] = fmaf(tv[k].x, tv[l].x, ass[i]);
                    ass[i] = fmaf(tv[k].y, tv[l].y, ass[i]);
                }
            }
        }
        #pragma unroll
        for (int i = 0; i < 36; ++i) {
            #pragma unroll
            for (int m = 32; m >= 1; m >>= 1) ass[i] += __shfl_xor(ass[i], m, 64);
        }
        if (lane == 0) {
            float* o = ws + TGT_OFF + (size_t)b * 36;
            #pragma unroll
            for (int i = 0; i < 36; ++i) o[i] = ass[i];
        }
    }
}

// 16 lanes per pair p: lanes 0-7 solve support Frechet (8-dim Gram coords),
// lanes 8-15 solve target Frechet for b = p%64 (redundant across s, but free ILP).
// Lane j owns row j of the normalized Gram; state a replicated per-lane.
__global__ __launch_bounds__(256) void solve_kernel(const float* __restrict__ ws,
                                                    float* __restrict__ out) {
    const int tid = threadIdx.x;
    const int p = blockIdx.x * 16 + (tid >> 4);
    const int j = tid & 7;
    const bool isTgt = (tid & 8) != 0;
    const float* __restrict__ G0 = isTgt ? (ws + TGT_OFF + (size_t)(p & (NB-1)) * 36)
                                         : (ws + (size_t)p * 100);
    // raw Gram row j (upper-tri packed), diag, inverse norms
    float Draw[8];
    #pragma unroll
    for (int k = 0; k < 8; ++k) {
        const int a_ = j < k ? j : k;
        const int b_ = j < k ? k : j;
        Draw[k] = G0[a_*8 + b_ - a_*(a_+1)/2];
    }
    float invn[8];
    #pragma unroll
    for (int k = 0; k < 8; ++k) {
        const float dkk = G0[k*8 + k - k*(k+1)/2];
        invn[k] = 1.f / fmaxf(sqrtf(fmaxf(dkk, 0.f)), 1e-7f);
    }
    const float djj = G0[j*8 + j - j*(j+1)/2];
    const float invn_own = 1.f / fmaxf(sqrtf(fmaxf(djj, 0.f)), 1e-7f);
    float Grow[8];
    #pragma unroll
    for (int k = 0; k < 8; ++k) Grow[k] = Draw[k] * invn_own * invn[k];

    // mu0 = normalize(mean X^): a_k = (1/8)/max(||mean||,1e-7), ||mean|| = sqrt(sum G)/8
    float rs = 0.f;
    #pragma unroll
    for (int k = 0; k < 8; ++k) rs += Grow[k];
    const float S = bfly8(rs);
    const float n0 = sqrtf(fmaxf(S, 0.f)) * 0.125f;
    const float r0 = 1.f / fmaxf(n0, 1e-7f);
    float a_own = 0.125f * r0;
    float aR[8];
    #pragma unroll
    for (int k = 0; k < 8; ++k) aR[k] = a_own;

    for (int it = 0; it < NITER; ++it) {
        float dot = 0.f;
        #pragma unroll
        for (int k = 0; k < 8; ++k) dot = fmaf(Grow[k], aR[k], dot);
        dot = fminf(fmaxf(dot, -1.f + 1e-6f), 1.f - 1e-6f);
        const float theta = acosf(dot);
        const float coef = (theta > 1e-4f) ? theta / sinf(theta) : 1.f;
        const float cdavg = 0.125f * bfly8(coef * dot);
        const float b_own = 0.125f * coef - cdavg * a_own;
        float bAll[8];
        #pragma unroll
        for (int k = 0; k < 8; ++k) bAll[k] = __shfl(b_own, k, 8);
        float Gb = 0.f;
        #pragma unroll
        for (int k = 0; k < 8; ++k) Gb = fmaf(Grow[k], bAll[k], Gb);
        const float vnsq = bfly8(b_own * Gb);            // ||v||^2 = b^T G b
        const float vn = sqrtf(fmaxf(vnsq, 0.f));
        const float sinc = (vn > 1e-9f) ? sinf(vn) / vn : 1.f;
        const float cosv = cosf(vn);
        const float c_own = cosv * a_own + sinc * b_own;
        float cAll[8];
        float Gc = 0.f;
        #pragma unroll
        for (int k = 0; k < 8; ++k) {
            cAll[k] = cosv * aR[k] + sinc * bAll[k];
            Gc = fmaf(Grow[k], cAll[k], Gc);
        }
        const float cn = sqrtf(fmaxf(bfly8(c_own * Gc), 0.f));  // ||mu_new||
        const float rn = 1.f / fmaxf(cn, 1e-7f);
        a_own = c_own * rn;
        #pragma unroll
        for (int k = 0; k < 8; ++k) aR[k] = cAll[k] * rn;
    }

    // sim = sum_{k,l} (a_sup_k/n_sup_k) Craw[k][l] (a_tgt_l/n_tgt_l)
    const float ahat = a_own * invn_own;
    float at[8];
    #pragma unroll
    for (int l = 0; l < 8; ++l) at[l] = __shfl(ahat, 8 + l, 16);  // tgt half's ahat
    const float* __restrict__ Crow = ws + (size_t)p * 100 + 36 + j*8;
    float tacc = 0.f;
    #pragma unroll
    for (int l = 0; l < 8; ++l) tacc = fmaf(Crow[l], at[l], tacc);
    float sim = ahat * tacc;
    sim += __shfl_xor(sim, 1, 8);
    sim += __shfl_xor(sim, 2, 8);
    sim += __shfl_xor(sim, 4, 8);
    if ((tid & 15) == 0) out[p] = sim;
}

extern "C" void kernel_launch(void* const* d_in, const int* in_sizes, int n_in,
                              void* d_out, int out_size, void* d_ws, size_t ws_size,
                              hipStream_t stream) {
    const float* sup = (const float*)d_in[0];   // [25,64,8,2048] f32
    const float* tgt = (const float*)d_in[1];   // [64,8,2048] f32
    float* ws = (float*)d_ws;                   // needs 649 KB
    float* out = (float*)d_out;                 // [25,64] f32
    gram_kernel<<<(NPAIR + NB) / 4, 256, 0, stream>>>(sup, tgt, ws);
    solve_kernel<<<NPAIR / 16, 256, 0, stream>>>(ws, out);
}

// Round 2
// 69.639 us; speedup vs baseline: 1.1132x; 1.1132x over previous
//
#include <hip/hip_runtime.h>
#include <math.h>

#define NFR 8
#define DD 2048
#define NS 25
#define NB 64
#define NPAIR (NS*NB)          // 1600
#define NITER 32

typedef __attribute__((ext_vector_type(8))) short short8;
typedef __attribute__((ext_vector_type(4))) float f32x4;

__device__ __forceinline__ float bfly8(float x) {
    x += __shfl_xor(x, 1, 8);
    x += __shfl_xor(x, 2, 8);
    x += __shfl_xor(x, 4, 8);
    return x;
}

// Split two f32 into packed-hi (truncated bf16) and packed-lo (bf16 of remainder).
__device__ __forceinline__ void split2(float a, float b, unsigned int& hi, unsigned int& lo) {
    unsigned int ua = __float_as_uint(a), ub = __float_as_uint(b);
    unsigned int ha = ua & 0xFFFF0000u, hb = ub & 0xFFFF0000u;
    hi = hb | (ha >> 16);
    float ra = a - __uint_as_float(ha);
    float rb = b - __uint_as_float(hb);
    lo = (__float_as_uint(rb) & 0xFFFF0000u) | (__float_as_uint(ra) >> 16);
}

// One block (4 waves) per (s,b) pair.
// Phase 1: 16x16 Gram of stacked rows [8 sup; 8 tgt] via bf16 hi/lo MFMA, split-K
//          across the 4 waves (512 each), LDS-reduced.
// Phase 2: lanes 0-7 solve support Frechet mean in 8-dim Gram coords, lanes 8-15
//          solve target Frechet (redundant across s, free), then cosine sim.
__global__ __launch_bounds__(256) void fused_kernel(const float* __restrict__ sup,
                                                    const float* __restrict__ tgt,
                                                    float* __restrict__ out) {
    const int p   = blockIdx.x;
    const int tid = threadIdx.x;
    const int wv  = tid >> 6;
    const int l   = tid & 63;
    const int row = l & 15;        // A/B fragment M-row (= Gram row content)
    const int kg  = l >> 4;        // k-group within 32-chunk

    __shared__ float part[4][16][17];
    __shared__ float graw[256];

    const float* rowp = (row < 8)
        ? sup + (size_t)p * (NFR*DD) + (size_t)row * DD
        : tgt + (size_t)(p & (NB-1)) * (NFR*DD) + (size_t)(row - 8) * DD;
    const float* ptr = rowp + wv * 512 + kg * 8;

    f32x4 accA = {0.f, 0.f, 0.f, 0.f};
    f32x4 accB = {0.f, 0.f, 0.f, 0.f};
    #pragma unroll 2
    for (int c = 0; c < 16; ++c) {
        float4 f0 = *(const float4*)(ptr);
        float4 f1 = *(const float4*)(ptr + 4);
        ptr += 32;
        union { unsigned int u[4]; short8 s; } H, L;
        split2(f0.x, f0.y, H.u[0], L.u[0]);
        split2(f0.z, f0.w, H.u[1], L.u[1]);
        split2(f1.x, f1.y, H.u[2], L.u[2]);
        split2(f1.z, f1.w, H.u[3], L.u[3]);
        accA = __builtin_amdgcn_mfma_f32_16x16x32_bf16(H.s, H.s, accA, 0, 0, 0);
        accB = __builtin_amdgcn_mfma_f32_16x16x32_bf16(H.s, L.s, accB, 0, 0, 0);
        accB = __builtin_amdgcn_mfma_f32_16x16x32_bf16(L.s, H.s, accB, 0, 0, 0);
    }
    // C layout: lane holds D[(l>>4)*4 + r][l&15]  (transpose harmless: Gram symmetric)
    #pragma unroll
    for (int r = 0; r < 4; ++r)
        part[wv][kg * 4 + r][row] = accA[r] + accB[r];
    __syncthreads();

    {
        const int rr = tid >> 4, cc = tid & 15;
        graw[rr * 16 + cc] = part[0][rr][cc] + part[1][rr][cc]
                           + part[2][rr][cc] + part[3][rr][cc];
    }
    __syncthreads();

    if (tid < 16) {
        const int j = tid & 7;
        const bool isTgt = tid >= 8;
        const int R = isTgt ? 8 + j : j;
        const int cb = isTgt ? 8 : 0;

        float invn[16];
        #pragma unroll
        for (int k = 0; k < 16; ++k)
            invn[k] = 1.f / fmaxf(sqrtf(fmaxf(graw[k * 16 + k], 0.f)), 1e-7f);
        const float invn_own = invn[R];

        float Grow[8];
        #pragma unroll
        for (int k = 0; k < 8; ++k)
            Grow[k] = graw[R * 16 + cb + k] * invn_own * invn[cb + k];

        // mu0 = normalize(mean X^)
        float rs = 0.f;
        #pragma unroll
        for (int k = 0; k < 8; ++k) rs += Grow[k];
        const float S = bfly8(rs);
        const float n0 = sqrtf(fmaxf(S, 0.f)) * 0.125f;
        const float r0 = 1.f / fmaxf(n0, 1e-7f);
        float a_own = 0.125f * r0;
        float aR[8];
        #pragma unroll
        for (int k = 0; k < 8; ++k) aR[k] = a_own;

        for (int it = 0; it < NITER; ++it) {
            float dot = 0.f;
            #pragma unroll
            for (int k = 0; k < 8; ++k) dot = fmaf(Grow[k], aR[k], dot);
            dot = fminf(fmaxf(dot, -1.f + 1e-6f), 1.f - 1e-6f);
            const float theta = acosf(dot);
            const float coef = (theta > 1e-4f) ? theta / sinf(theta) : 1.f;
            const float cdavg = 0.125f * bfly8(coef * dot);
            const float b_own = 0.125f * coef - cdavg * a_own;
            float bAll[8];
            #pragma unroll
            for (int k = 0; k < 8; ++k) bAll[k] = __shfl(b_own, (tid & 8) + k, 16);
            float Gb = 0.f;
            #pragma unroll
            for (int k = 0; k < 8; ++k) Gb = fmaf(Grow[k], bAll[k], Gb);
            const float vnsq = bfly8(b_own * Gb);            // ||v||^2 = b^T G b
            const float vn = sqrtf(fmaxf(vnsq, 0.f));
            const float sinc = (vn > 1e-9f) ? sinf(vn) / vn : 1.f;
            const float cosv = cosf(vn);
            const float c_own = cosv * a_own + sinc * b_own;
            float cAll[8];
            float Gc = 0.f;
            #pragma unroll
            for (int k = 0; k < 8; ++k) {
                cAll[k] = cosv * aR[k] + sinc * bAll[k];
                Gc = fmaf(Grow[k], cAll[k], Gc);
            }
            const float cn = sqrtf(fmaxf(bfly8(c_own * Gc), 0.f));
            const float rn = 1.f / fmaxf(cn, 1e-7f);
            a_own = c_own * rn;
            #pragma unroll
            for (int k = 0; k < 8; ++k) aR[k] = cAll[k] * rn;
        }

        // sim = sum_{j,l} ahat_sup_j * Craw[j][l] * ahat_tgt_l
        const float ahat = a_own * invn_own;
        float at[8];
        #pragma unroll
        for (int q = 0; q < 8; ++q) at[q] = __shfl(ahat, 8 + q, 16);
        float tacc = 0.f;
        #pragma unroll
        for (int q = 0; q < 8; ++q) tacc = fmaf(graw[j * 16 + 8 + q], at[q], tacc);
        float sim = ahat * tacc;
        sim += __shfl_xor(sim, 1, 8);
        sim += __shfl_xor(sim, 2, 8);
        sim += __shfl_xor(sim, 4, 8);
        if (tid == 0) out[p] = sim;
    }
}

extern "C" void kernel_launch(void* const* d_in, const int* in_sizes, int n_in,
                              void* d_out, int out_size, void* d_ws, size_t ws_size,
                              hipStream_t stream) {
    const float* sup = (const float*)d_in[0];   // [25,64,8,2048] f32
    const float* tgt = (const float*)d_in[1];   // [64,8,2048] f32
    float* out = (float*)d_out;                 // [25,64] f32
    fused_kernel<<<NPAIR, 256, 0, stream>>>(sup, tgt, out);
}

// Round 3
// 50.416 us; speedup vs baseline: 1.5376x; 1.3813x over previous
//
#include <hip/hip_runtime.h>
#include <math.h>

#define NFR 8
#define DD 2048
#define NS 25
#define NB 64
#define NPAIR (NS*NB)          // 1600
#define NITER 32

typedef __attribute__((ext_vector_type(8))) short short8;
typedef __attribute__((ext_vector_type(4))) float f32x4;

// Branch-free acos, ~1e-7 rel (Cephes asinf core). Valid for |x| <= 1.
__device__ __forceinline__ float acos_fast(float x) {
    const float ax = fabsf(x);
    const bool big = ax > 0.5f;
    const float z = big ? 0.5f * (1.f - ax) : x * x;
    const float s = big ? sqrtf(z) : ax;
    float p = fmaf(z, 4.2163199048e-2f, 2.4181311049e-2f);
    p = fmaf(z, p, 4.5470025998e-2f);
    p = fmaf(z, p, 7.4953002686e-2f);
    p = fmaf(z, p, 1.6666752422e-1f);
    const float asin_s = fmaf(s * z, p, s);
    const float asin_abs = big ? (1.5707963267948966f - 2.f * asin_s) : asin_s;
    return 1.5707963267948966f - copysignf(asin_abs, x);
}

// Split two f32 into packed-hi (truncated bf16) and packed-lo (bf16 of remainder).
__device__ __forceinline__ void split2(float a, float b, unsigned int& hi, unsigned int& lo) {
    unsigned int ua = __float_as_uint(a), ub = __float_as_uint(b);
    unsigned int ha = ua & 0xFFFF0000u, hb = ub & 0xFFFF0000u;
    hi = hb | (ha >> 16);
    float ra = a - __uint_as_float(ha);
    float rb = b - __uint_as_float(hb);
    lo = (__float_as_uint(rb) & 0xFFFF0000u) | (__float_as_uint(ra) >> 16);
}

// One block (4 waves) per (s,b) pair.
// Phase 1: 16x16 Gram of stacked rows [8 sup; 8 tgt] via bf16 hi/lo MFMA, split-K.
// Phase 2: lanes 0-7 solve support Frechet in 8-dim Gram coords, lanes 8-15 target.
__global__ __launch_bounds__(256) void fused_kernel(const float* __restrict__ sup,
                                                    const float* __restrict__ tgt,
                                                    float* __restrict__ out) {
    const int p   = blockIdx.x;
    const int tid = threadIdx.x;
    const int wv  = tid >> 6;
    const int l   = tid & 63;
    const int row = l & 15;
    const int kg  = l >> 4;

    __shared__ float part[4][16][17];
    __shared__ float graw[256];

    const float* rowp = (row < 8)
        ? sup + (size_t)p * (NFR*DD) + (size_t)row * DD
        : tgt + (size_t)(p & (NB-1)) * (NFR*DD) + (size_t)(row - 8) * DD;
    const float* ptr = rowp + wv * 512 + kg * 8;

    f32x4 accA = {0.f, 0.f, 0.f, 0.f};
    f32x4 accB = {0.f, 0.f, 0.f, 0.f};
    #pragma unroll 2
    for (int c = 0; c < 16; ++c) {
        float4 f0 = *(const float4*)(ptr);
        float4 f1 = *(const float4*)(ptr + 4);
        ptr += 32;
        union { unsigned int u[4]; short8 s; } H, L;
        split2(f0.x, f0.y, H.u[0], L.u[0]);
        split2(f0.z, f0.w, H.u[1], L.u[1]);
        split2(f1.x, f1.y, H.u[2], L.u[2]);
        split2(f1.z, f1.w, H.u[3], L.u[3]);
        accA = __builtin_amdgcn_mfma_f32_16x16x32_bf16(H.s, H.s, accA, 0, 0, 0);
        accB = __builtin_amdgcn_mfma_f32_16x16x32_bf16(H.s, L.s, accB, 0, 0, 0);
        accB = __builtin_amdgcn_mfma_f32_16x16x32_bf16(L.s, H.s, accB, 0, 0, 0);
    }
    #pragma unroll
    for (int r = 0; r < 4; ++r)
        part[wv][kg * 4 + r][row] = accA[r] + accB[r];
    __syncthreads();

    {
        const int rr = tid >> 4, cc = tid & 15;
        graw[rr * 16 + cc] = part[0][rr][cc] + part[1][rr][cc]
                           + part[2][rr][cc] + part[3][rr][cc];
    }
    __syncthreads();

    if (tid < 16) {
        const int j = tid & 7;
        const int base = tid & 8;              // 0 for sup half, 8 for tgt half
        const int R = base + j;
        const int cb = base;

        const float invn_own = rsqrtf(fmaxf(graw[R * 16 + R], 1e-14f));
        float Grow[8];
        #pragma unroll
        for (int k = 0; k < 8; ++k) {
            const float invk = rsqrtf(fmaxf(graw[(cb + k) * 16 + (cb + k)], 1e-14f));
            Grow[k] = graw[R * 16 + cb + k] * invn_own * invk;
        }

        // mu0 = normalize(mean X^): a_k = rsqrt(sum G)
        float rs = 0.f;
        #pragma unroll
        for (int k = 0; k < 8; ++k) rs += Grow[k];
        rs += __shfl_xor(rs, 1, 8);
        rs += __shfl_xor(rs, 2, 8);
        rs += __shfl_xor(rs, 4, 8);
        float a_own = rsqrtf(fmaxf(rs, 6.4e-13f));
        float aAll[8];
        #pragma unroll
        for (int k = 0; k < 8; ++k) aAll[k] = a_own;

        for (int it = 0; it < NITER; ++it) {
            float dot = 0.f;
            #pragma unroll
            for (int k = 0; k < 8; ++k) dot = fmaf(Grow[k], aAll[k], dot);
            dot = fminf(fmaxf(dot, -1.f + 1e-6f), 1.f - 1e-6f);
            const float theta = acos_fast(dot);
            const float q = fmaf(-dot, dot, 1.0f);          // sin^2(theta)
            const float coef = (theta > 1e-4f) ? theta * rsqrtf(q) : 1.f;
            const float w = 0.125f * coef;
            float wAll[8];
            #pragma unroll
            for (int k = 0; k < 8; ++k) wAll[k] = __shfl(w, base + k, 16);
            float Gw = 0.f;
            #pragma unroll
            for (int k = 0; k < 8; ++k) Gw = fmaf(Grow[k], wAll[k], Gw);
            // two interleaved 8-lane reductions: cdavg = a^T G w, wGw = w^T G w
            float u1 = a_own * Gw, u2 = w * Gw;
            u1 += __shfl_xor(u1, 1, 8);  u2 += __shfl_xor(u2, 1, 8);
            u1 += __shfl_xor(u1, 2, 8);  u2 += __shfl_xor(u2, 2, 8);
            u1 += __shfl_xor(u1, 4, 8);  u2 += __shfl_xor(u2, 4, 8);
            const float cdavg = u1;
            const float vnsq = fmaxf(u2 - cdavg * cdavg, 0.f);   // ||v||^2
            const float vn = sqrtf(vnsq);
            const float rev = vn * 0.15915494309189535f;
            const float sinv = __builtin_amdgcn_sinf(rev);       // sin(vn)
            const float cosv = __builtin_amdgcn_cosf(rev);       // cos(vn)
            const float sinc = (vn > 1e-9f) ? sinv / vn : 1.f;
            // ||mu_new||^2 = cos^2 + sinc^2 * ||v||^2  (a^T G b = 0 algebraically)
            const float cn2 = fmaf(sinc * sinc, vnsq, cosv * cosv);
            const float rn = rsqrtf(fmaxf(cn2, 1e-14f));
            a_own = (cosv * a_own + sinc * fmaf(-cdavg, a_own, w)) * rn;
            #pragma unroll
            for (int k = 0; k < 8; ++k)
                aAll[k] = (cosv * aAll[k] + sinc * fmaf(-cdavg, aAll[k], wAll[k])) * rn;
        }

        // sim = sum_{j,l} ahat_sup_j * Craw[j][l] * ahat_tgt_l
        const float ahat = a_own * invn_own;
        float at[8];
        #pragma unroll
        for (int q2 = 0; q2 < 8; ++q2) at[q2] = __shfl(ahat, 8 + q2, 16);
        float tacc = 0.f;
        #pragma unroll
        for (int q2 = 0; q2 < 8; ++q2) tacc = fmaf(graw[j * 16 + 8 + q2], at[q2], tacc);
        float sim = ahat * tacc;
        sim += __shfl_xor(sim, 1, 8);
        sim += __shfl_xor(sim, 2, 8);
        sim += __shfl_xor(sim, 4, 8);
        if (tid == 0) out[p] = sim;
    }
}

extern "C" void kernel_launch(void* const* d_in, const int* in_sizes, int n_in,
                              void* d_out, int out_size, void* d_ws, size_t ws_size,
                              hipStream_t stream) {
    const float* sup = (const float*)d_in[0];   // [25,64,8,2048] f32
    const float* tgt = (const float*)d_in[1];   // [64,8,2048] f32
    float* out = (float*)d_out;                 // [25,64] f32
    fused_kernel<<<NPAIR, 256, 0, stream>>>(sup, tgt, out);
}